// Round 20
// baseline (249.505 us; speedup 1.0000x reference)
//
#include <hip/hip_runtime.h>
#include <hip/hip_bf16.h>
#include <cmath>

#define DIM 512
#define HID 256
#define ROWS_PB 16       // rows per block (100000 = 6250 * 16, no tail)
#define NCHUNK 16        // K chunks of 32
#define CB 16384         // B chunk bytes: 32k * 256c * 2B

typedef __attribute__((ext_vector_type(8))) short short8;
typedef __attribute__((ext_vector_type(4))) float f32x4;

#define AS1 __attribute__((address_space(1)))
#define AS3 __attribute__((address_space(3)))

__device__ __forceinline__ unsigned short f2bf(float f) {
  union { float f; unsigned u; } v; v.f = f;
  unsigned u = v.u;
  return (unsigned short)((u + 0x7FFFu + ((u >> 16) & 1u)) >> 16);
}

// Pre-swizzle W1 (fp32 [512,256] row-major) into bf16 MFMA fragment order:
// w1s[((k>>3)*HID + c)*8 + (k&7)]. K-chunk c (32 k's) is the contiguous
// 16 KB at byte offset c*16384 — a linear global_load_lds copy.
__global__ void w1_swz_kernel(const float* __restrict__ W1,
                              unsigned short* __restrict__ w1s) {
  int tid = blockIdx.x * blockDim.x + threadIdx.x;
  if (tid >= DIM * HID) return;
  int k = tid / HID;
  int c = tid - k * HID;
  w1s[(((k >> 3) * HID) + c) * 8 + (k & 7)] = f2bf(W1[tid]);
}

__device__ __forceinline__ short8 cvt8(const f32x4 p0, const f32x4 p1) {
  short8 r;
  r[0] = (short)f2bf(p0[0]); r[1] = (short)f2bf(p0[1]);
  r[2] = (short)f2bf(p0[2]); r[3] = (short)f2bf(p0[3]);
  r[4] = (short)f2bf(p1[0]); r[5] = (short)f2bf(p1[1]);
  r[6] = (short)f2bf(p1[2]); r[7] = (short)f2bf(p1[3]);
  return r;
}

// 4 waves / 16 rows. Wave w: src s=w&1 (z1/z2), hid-half h=w>>1.
// A: burst-loaded from HBM straight into af[16] regs (4 groups of 4 chunks
//    to bound transient pressure — R10/R17 spill lesson). No Az LDS.
// B: m97-style global_load_lds double buffer, ONE __syncthreads per chunk.
// K-loop: L2-only, 8 ds_read + 8 MFMA per chunk per wave.
// LDS 33 KB + (256,3) -> 3 blocks/CU (12 waves/CU): resident blocks cover
// each other's barrier drains.
// Epilogue: z re-read from L2-hot lines, fp32 end-to-end.
__global__ __launch_bounds__(256, 3) void fa_main_kernel(
    const float* __restrict__ z1, const float* __restrict__ z2,
    const unsigned short* __restrict__ w1s,
    const float* __restrict__ bias1, const float* __restrict__ W2,
    const float* __restrict__ bias2, float* __restrict__ out, int n) {
  __shared__ char smem[2 * CB + 256];       // B dbuf 32 KB; xs2 @ +32768
  float* xs2 = (float*)(smem + 2 * CB);     // [s*2+h][16 rows]

  const int t = threadIdx.x;
  const int w = t >> 6;
  const int l = t & 63;
  const int l15 = l & 15, l16 = l >> 4;
  const int s = w & 1;   // source this wave scores
  const int h = w >> 1;  // hid-half this wave computes
  const int row0 = blockIdx.x * ROWS_PB;
  int myrow = row0 + l15;
  const bool rok = myrow < n;
  if (!rok) myrow = n - 1;
  const float* zz = s ? z2 : z1;
  const float* ap = zz + (size_t)myrow * DIM + (l16 << 3);
  const f32x4 zf4 = (f32x4){0.f, 0.f, 0.f, 0.f};

  auto STAGE = [&](int cc, int buf) {
    const char* gsrc = (const char*)w1s + cc * CB + l * 16;
    char* ldst = smem + buf * CB;
#pragma unroll
    for (int r = 0; r < 4; ++r) {
      const int rr = w + r * 4;
      __builtin_amdgcn_global_load_lds(
          (const AS1 void*)(gsrc + rr * 1024),
          (AS3 void*)(ldst + rr * 1024), 16, 0, 0);
    }
  };

  // B[0] first (L2 latency overlaps the A burst), then A in 4 groups of 4.
  STAGE(0, 0);
  __builtin_amdgcn_sched_barrier(0);
  short8 af[NCHUNK];
#pragma unroll
  for (int g = 0; g < 4; ++g) {
    f32x4 p[4][2];
#pragma unroll
    for (int j = 0; j < 4; ++j) {
      const float* pp = ap + (((g << 2) + j) << 5);
      p[j][0] = rok ? *(const f32x4*)(pp) : zf4;
      p[j][1] = rok ? *(const f32x4*)(pp + 4) : zf4;
    }
#pragma unroll
    for (int j = 0; j < 4; ++j) af[(g << 2) + j] = cvt8(p[j][0], p[j][1]);
  }

  f32x4 acc[8];
#pragma unroll
  for (int f = 0; f < 8; ++f) acc[f] = zf4;

  __syncthreads();  // B[0] + (incidentally) the A burst drained

  // K-loop: ONE barrier per chunk. STAGE(c+1) -> 8 ds_read + 8 MFMA -> sync.
#pragma unroll
  for (int c = 0; c < NCHUNK; ++c) {
    if (c + 1 < NCHUNK) STAGE(c + 1, (c + 1) & 1);
    __builtin_amdgcn_sched_barrier(0);  // pin stage issue above compute
    const short8* bp =
        (const short8*)(smem + (c & 1) * CB) + (l16 << 8) + (h << 7) + l15;
#pragma unroll
    for (int f = 0; f < 8; ++f)
      acc[f] = __builtin_amdgcn_mfma_f32_16x16x32_bf16(af[c], bp[f << 4],
                                                       acc[f], 0, 0, 0);
    __syncthreads();  // publishes buf^1; buf reads complete before overwrite
  }

  // Partial logit over this wave's hid-half.
  // C/D: hidden col = h*128 + f*16 + l15, row-in-tile = l16*4 + r.
  float part[4] = {0.f, 0.f, 0.f, 0.f};
#pragma unroll
  for (int f = 0; f < 8; ++f) {
    const int cc = (h << 7) + (f << 4) + l15;
    const float w2v = W2[cc];
    const float b1v = bias1[cc];
#pragma unroll
    for (int r = 0; r < 4; ++r) {
      const float hh = acc[f][r] + b1v;
      part[r] += (hh > 0.f) ? hh * w2v : 0.f;
    }
  }
#pragma unroll
  for (int r = 0; r < 4; ++r) {
#pragma unroll
    for (int m = 1; m < 16; m <<= 1) part[r] += __shfl_xor(part[r], m, 16);
  }
  if (l15 == 0) {
#pragma unroll
    for (int r = 0; r < 4; ++r)
      xs2[((s << 1) + h) * ROWS_PB + (l16 << 2) + r] = part[r];
  }
  __syncthreads();

  // Epilogue: flat 16x512 tile, 8 f32x4 per thread; z re-read is L2-hot.
#pragma unroll
  for (int j = 0; j < 8; ++j) {
    const int idx = j * 256 + t;      // f32x4 index in the 16x128 grid
    const int row = idx >> 7;
    const int c4 = idx & 127;
    const int grow = row0 + row;
    if (grow < n) {
      const float x = xs2[row] + xs2[ROWS_PB + row];
      const float y = xs2[2 * ROWS_PB + row] + xs2[3 * ROWS_PB + row];
      const float sx = 1.f / (1.f + __expf(y - x));  // b2 cancels
      const float sy = 1.f - sx;
      const size_t off = (size_t)grow * DIM + ((size_t)c4 << 2);
      const f32x4 a4 = *(const f32x4*)(z1 + off);
      const f32x4 b4 = *(const f32x4*)(z2 + off);
      f32x4 ov;
      ov[0] = sx * a4[0] + sy * b4[0];
      ov[1] = sx * a4[1] + sy * b4[1];
      ov[2] = sx * a4[2] + sy * b4[2];
      ov[3] = sx * a4[3] + sy * b4[3];
      *(f32x4*)(out + off) = ov;
    }
  }
}

extern "C" void kernel_launch(void* const* d_in, const int* in_sizes, int n_in,
                              void* d_out, int out_size, void* d_ws,
                              size_t ws_size, hipStream_t stream) {
  const float* z1 = (const float*)d_in[0];
  const float* z2 = (const float*)d_in[1];
  const float* W1 = (const float*)d_in[2];
  const float* b1 = (const float*)d_in[3];
  const float* W2 = (const float*)d_in[4];
  const float* b2 = (const float*)d_in[5];
  float* out = (float*)d_out;
  const int n = in_sizes[0] / DIM;
  unsigned short* w1s = (unsigned short*)d_ws;  // 512*256*2 = 256 KB

  hipLaunchKernelGGL(w1_swz_kernel, dim3((DIM * HID + 255) / 256), dim3(256),
                     0, stream, W1, w1s);
  const int nwg = (n + ROWS_PB - 1) / ROWS_PB;
  hipLaunchKernelGGL(fa_main_kernel, dim3(nwg), dim3(256), 0, stream, z1, z2,
                     w1s, b1, W2, b2, out, n);
}